// Round 2
// baseline (540.138 us; speedup 1.0000x reference)
//
#include <hip/hip_runtime.h>
#include <math.h>

#define NBINS 64
#define RADIUS 3
#define WIN (2*RADIUS+1)
#define HIST_ELEMS (NBINS*NBINS)
#define LROW 70          // padded LDS row: bins -3..66
#define LSIZE (LROW*LROW)
// exponent in bin units: -(u-b)^2 * 8192/63^2, converted to exp2: * log2(e)
#define K2 2.9777244f

// ---- monotone float<->uint keys ----
static __device__ __forceinline__ unsigned f2key(float f) {
    unsigned u = __float_as_uint(f);
    return (u & 0x80000000u) ? ~u : (u | 0x80000000u);
}
static __device__ __forceinline__ float key2f(unsigned u) {
    return (u & 0x80000000u) ? __uint_as_float(u & 0x7fffffffu) : __uint_as_float(~u);
}

// ws layout: [0..7] uint minmax keys (idx = n*4 + tensor*2 + {0:min,1:max})
//            at byte offset 256: float hist[2][64*64]
__global__ void init_ws_kernel(unsigned* __restrict__ mm, float* __restrict__ hist) {
    int i = blockIdx.x * blockDim.x + threadIdx.x;
    if (i < 8) mm[i] = (i & 1) ? 0u : 0xFFFFFFFFu;
    for (int j = i; j < 2 * HIST_ELEMS; j += gridDim.x * blockDim.x) hist[j] = 0.0f;
}

__global__ __launch_bounds__(256) void minmax_kernel(const float* __restrict__ tar,
                                                     const float* __restrict__ src,
                                                     unsigned* __restrict__ mm, int P) {
    const int n = blockIdx.y;
    const int t = blockIdx.z;
    const float* x = (t == 0 ? tar : src) + (size_t)n * P;
    float lmin = INFINITY, lmax = -INFINITY;
    for (int i = blockIdx.x * blockDim.x + threadIdx.x; i < P; i += gridDim.x * blockDim.x) {
        float v = x[i];
        lmin = fminf(lmin, v);
        lmax = fmaxf(lmax, v);
    }
    for (int off = 32; off > 0; off >>= 1) {
        lmin = fminf(lmin, __shfl_down(lmin, off, 64));
        lmax = fmaxf(lmax, __shfl_down(lmax, off, 64));
    }
    __shared__ float smin[4], smax[4];
    const int lane = threadIdx.x & 63, wave = threadIdx.x >> 6;
    if (lane == 0) { smin[wave] = lmin; smax[wave] = lmax; }
    __syncthreads();
    if (threadIdx.x == 0) {
        float m = fminf(fminf(smin[0], smin[1]), fminf(smin[2], smin[3]));
        float M = fmaxf(fmaxf(smax[0], smax[1]), fmaxf(smax[2], smax[3]));
        atomicMin(&mm[(n * 2 + t) * 2 + 0], f2key(m));
        atomicMax(&mm[(n * 2 + t) * 2 + 1], f2key(M));
    }
}

__global__ __launch_bounds__(512) void hist_kernel(const float* __restrict__ tar,
                                                   const float* __restrict__ src,
                                                   const unsigned* __restrict__ mm,
                                                   float* __restrict__ ghist, int P) {
    const int n = blockIdx.y;
    __shared__ float lh[LSIZE];
    for (int i = threadIdx.x; i < LSIZE; i += blockDim.x) lh[i] = 0.0f;
    __syncthreads();

    const float tmin = key2f(mm[n * 4 + 0]);
    const float tmax = key2f(mm[n * 4 + 1]);
    const float smin = key2f(mm[n * 4 + 2]);
    const float smax = key2f(mm[n * 4 + 3]);
    const float tscale = 63.0f / (tmax - tmin + 1e-10f);
    const float sscale = 63.0f / (smax - smin + 1e-10f);
    const float* t = tar + (size_t)n * P;
    const float* s = src + (size_t)n * P;

    for (int i = blockIdx.x * blockDim.x + threadIdx.x; i < P; i += gridDim.x * blockDim.x) {
        float ut = (t[i] - tmin) * tscale;   // [0, 63] in bin units
        float us = (s[i] - smin) * sscale;
        int ct = __float2int_rn(ut);
        int cs = __float2int_rn(us);
        float ft = ut - (float)ct;           // [-0.5, 0.5]
        float fs = us - (float)cs;

        float wt[WIN], ws[WIN];
        #pragma unroll
        for (int k = 0; k < WIN; ++k) {
            float dt = ft - (float)(k - RADIUS);
            float ds = fs - (float)(k - RADIUS);
            wt[k] = exp2f(-K2 * dt * dt);
            ws[k] = exp2f(-K2 * ds * ds);
        }
        // padded base: row (ct-3)+3 = ct, col (cs-3)+3 = cs
        float* base = &lh[ct * LROW + cs];
        #pragma unroll
        for (int k = 0; k < WIN; ++k) {
            float w = wt[k];
            #pragma unroll
            for (int j = 0; j < WIN; ++j) {
                unsafeAtomicAdd(&base[k * LROW + j], w * ws[j]);
            }
        }
    }
    __syncthreads();
    // flush interior (bins 0..63 live at padded index +3)
    float* gh = ghist + (size_t)n * HIST_ELEMS;
    for (int i = threadIdx.x; i < HIST_ELEMS; i += blockDim.x) {
        int b = i >> 6, c = i & 63;
        float v = lh[(b + RADIUS) * LROW + (c + RADIUS)];
        if (v != 0.0f) unsafeAtomicAdd(&gh[i], v);
    }
}

static __device__ __forceinline__ float block_reduce_sum(float v, float* buf) {
    for (int off = 32; off > 0; off >>= 1) v += __shfl_down(v, off, 64);
    const int lane = threadIdx.x & 63, wave = threadIdx.x >> 6;
    __syncthreads();
    if (lane == 0) buf[wave] = v;
    __syncthreads();
    return buf[0] + buf[1] + buf[2] + buf[3];
}

__global__ __launch_bounds__(256) void finalize_kernel(const float* __restrict__ ghist,
                                                       float* __restrict__ out) {
    __shared__ float buf[4];
    __shared__ float colp[4][NBINS];
    __shared__ float rowsum[NBINS], colsum[NBINS];
    const int tid = threadIdx.x;
    float acc = 0.0f;
    for (int n = 0; n < 2; ++n) {
        const float* h = ghist + n * HIST_ELEMS;
        // row sums: thread -> quarter-row, combine within lane-quad
        {
            int r = tid >> 2, q = tid & 3;
            const float* hp = h + r * NBINS + q * 16;
            float sv = 0.0f;
            #pragma unroll
            for (int k = 0; k < 16; ++k) sv += hp[k];
            sv += __shfl_down(sv, 1, 64);
            sv += __shfl_down(sv, 2, 64);
            if (q == 0) rowsum[r] = sv;
        }
        // col partial sums: thread -> 16 rows of one column
        {
            int c = tid & 63, g = tid >> 6;
            const float* hp = h + (g * 16) * NBINS + c;
            float sv = 0.0f;
            #pragma unroll
            for (int k = 0; k < 16; ++k) sv += hp[k * NBINS];
            colp[g][c] = sv;
        }
        __syncthreads();
        if (tid < NBINS)
            colsum[tid] = colp[0][tid] + colp[1][tid] + colp[2][tid] + colp[3][tid];
        __syncthreads();

        float tv = (tid < NBINS) ? rowsum[tid] : 0.0f;
        float total = block_reduce_sum(tv, buf);
        float inv = 1.0f / total;

        float ej = 0.0f;
        for (int i = tid; i < HIST_ELEMS; i += 256) {
            float p = h[i] * inv;
            ej += p * __logf(p + 1e-10f);
        }
        float entj = -block_reduce_sum(ej, buf);

        float em = 0.0f;
        if (tid < NBINS) {
            float p = rowsum[tid] * inv;
            em = p * __logf(p + 1e-10f);
        } else if (tid < 2 * NBINS) {
            float p = colsum[tid - NBINS] * inv;
            em = p * __logf(p + 1e-10f);
        }
        float ents = -block_reduce_sum(em, buf);

        acc += ents / entj;
        __syncthreads();
    }
    if (tid == 0) out[0] = -0.5f * acc;
}

extern "C" void kernel_launch(void* const* d_in, const int* in_sizes, int n_in,
                              void* d_out, int out_size, void* d_ws, size_t ws_size,
                              hipStream_t stream) {
    const float* tar = (const float*)d_in[0];
    const float* src = (const float*)d_in[1];
    const int N = 2;
    const int P = in_sizes[0] / N;  // 96*96*96 = 884736

    unsigned* mm = (unsigned*)d_ws;
    float* hist = (float*)((char*)d_ws + 256);
    float* out = (float*)d_out;

    init_ws_kernel<<<33, 256, 0, stream>>>(mm, hist);
    minmax_kernel<<<dim3(64, N, 2), 256, 0, stream>>>(tar, src, mm, P);
    hist_kernel<<<dim3(256, N, 1), 512, 0, stream>>>(tar, src, mm, hist, P);
    finalize_kernel<<<1, 256, 0, stream>>>(hist, out);
}

// Round 3
// 175.376 us; speedup vs baseline: 3.0799x; 3.0799x over previous
//
#include <hip/hip_runtime.h>
#include <math.h>

#define NBINS 64
#define HIST_ELEMS (NBINS*NBINS)
#define PTS_PER_BLOCK 4096
#define MEGA 1024
#define MEGAS (PTS_PER_BLOCK/MEGA)
#define GX 216                 // 216 * 4096 = 884736 = P exactly
// exponent: -(u_bins - b)^2 * (8192/63^2) in log2 domain: K2 = 8192/3969*log2(e)
#define SQK 1.7256062f         // sqrt(K2); store u*SQK so weight = exp2(-(uh - bh)^2)

typedef float f4 __attribute__((ext_vector_type(4)));
typedef float f32x4 __attribute__((ext_vector_type(4)));
typedef _Float16 half8 __attribute__((ext_vector_type(8)));
typedef int int4v __attribute__((ext_vector_type(4)));

// ---- monotone float<->uint keys ----
static __device__ __forceinline__ unsigned f2key(float f) {
    unsigned u = __float_as_uint(f);
    return (u & 0x80000000u) ? ~u : (u | 0x80000000u);
}
static __device__ __forceinline__ float key2f(unsigned u) {
    return (u & 0x80000000u) ? __uint_as_float(u & 0x7fffffffu) : __uint_as_float(~u);
}

static __device__ __forceinline__ half8 pack8(const float* w) {
    int4v v;
    v[0] = __builtin_bit_cast(int, __builtin_amdgcn_cvt_pkrtz(w[0], w[1]));
    v[1] = __builtin_bit_cast(int, __builtin_amdgcn_cvt_pkrtz(w[2], w[3]));
    v[2] = __builtin_bit_cast(int, __builtin_amdgcn_cvt_pkrtz(w[4], w[5]));
    v[3] = __builtin_bit_cast(int, __builtin_amdgcn_cvt_pkrtz(w[6], w[7]));
    return __builtin_bit_cast(half8, v);
}

// ws layout: [0..7] uint minmax keys | @256: float hist[2][4096] | @33024: float bh[432][4096]
__global__ void init_ws_kernel(unsigned* __restrict__ mm, float* __restrict__ hist) {
    int i = threadIdx.x;
    if (i < 8) mm[i] = (i & 1) ? 0u : 0xFFFFFFFFu;
    f4* h4 = (f4*)hist;
    f4 z = {0.f, 0.f, 0.f, 0.f};
    for (int j = i; j < 2 * HIST_ELEMS / 4; j += blockDim.x) h4[j] = z;
}

__global__ __launch_bounds__(256) void minmax_kernel(const float* __restrict__ tar,
                                                     const float* __restrict__ src,
                                                     unsigned* __restrict__ mm, int P) {
    const int n = blockIdx.y;
    const int t = blockIdx.z;
    const f4* x = (const f4*)((t == 0 ? tar : src) + (size_t)n * P);
    const int n4 = P / 4;
    float lmin = INFINITY, lmax = -INFINITY;
    for (int i = blockIdx.x * blockDim.x + threadIdx.x; i < n4; i += gridDim.x * blockDim.x) {
        f4 v = x[i];
        lmin = fminf(lmin, fminf(fminf(v[0], v[1]), fminf(v[2], v[3])));
        lmax = fmaxf(lmax, fmaxf(fmaxf(v[0], v[1]), fmaxf(v[2], v[3])));
    }
    for (int off = 32; off > 0; off >>= 1) {
        lmin = fminf(lmin, __shfl_down(lmin, off, 64));
        lmax = fmaxf(lmax, __shfl_down(lmax, off, 64));
    }
    __shared__ float smin[4], smax[4];
    const int lane = threadIdx.x & 63, wave = threadIdx.x >> 6;
    if (lane == 0) { smin[wave] = lmin; smax[wave] = lmax; }
    __syncthreads();
    if (threadIdx.x == 0) {
        float m = fminf(fminf(smin[0], smin[1]), fminf(smin[2], smin[3]));
        float M = fmaxf(fmaxf(smax[0], smax[1]), fmaxf(smax[2], smax[3]));
        atomicMin(&mm[(n * 2 + t) * 2 + 0], f2key(m));
        atomicMax(&mm[(n * 2 + t) * 2 + 1], f2key(M));
    }
}

// Joint histogram as 64x64xP GEMM via MFMA f16.
// A[m][k] = wt(point k, tar bin m); B[k][n] = ws(point k, src bin n).
// v_mfma_f32_16x16x32_f16 layouts: A: m=lane&15, k=quad*8+j; B: n=lane&15, k=quad*8+j;
// C/D: col=lane&15, row=quad*4+reg.
__global__ __launch_bounds__(256) void mfma_hist_kernel(const float* __restrict__ tar,
                                                        const float* __restrict__ src,
                                                        const unsigned* __restrict__ mm,
                                                        float* __restrict__ bh,
                                                        float* __restrict__ hist,
                                                        int P, int staged) {
    const int n = blockIdx.y;
    const int bx = blockIdx.x;
    const int tid = threadIdx.x;
    const int lane = tid & 63, wave = tid >> 6;
    const int mlane = lane & 15, quad = lane >> 4;

    __shared__ float su_t[MEGA], su_s[MEGA];
    __shared__ float lh[HIST_ELEMS];
    {   // zero lh (used only in epilogue; barriers in main loop order it)
        f4 z = {0.f, 0.f, 0.f, 0.f};
        f4* l4 = (f4*)lh;
        for (int i = tid; i < HIST_ELEMS / 4; i += 256) l4[i] = z;
    }

    const float tmin = key2f(mm[n * 4 + 0]);
    const float tmax = key2f(mm[n * 4 + 1]);
    const float smin = key2f(mm[n * 4 + 2]);
    const float smax = key2f(mm[n * 4 + 3]);
    const float tk = 63.0f / (tmax - tmin + 1e-10f) * SQK;  // x -> scaled bin units
    const float sk = 63.0f / (smax - smin + 1e-10f) * SQK;

    const float* t = tar + (size_t)n * P + (size_t)bx * PTS_PER_BLOCK;
    const float* s = src + (size_t)n * P + (size_t)bx * PTS_PER_BLOCK;

    float mhat[4];
    #pragma unroll
    for (int mt = 0; mt < 4; ++mt) mhat[mt] = (float)(mlane + 16 * mt) * SQK;

    f32x4 acc[4][4];
    #pragma unroll
    for (int a = 0; a < 4; ++a)
        #pragma unroll
        for (int b = 0; b < 4; ++b) acc[a][b] = (f32x4){0.f, 0.f, 0.f, 0.f};

    for (int mega = 0; mega < MEGAS; ++mega) {
        // --- load phase: 256 threads x 1 float4 each per tensor ---
        const int pb = mega * MEGA + tid * 4;
        f4 tv = *(const f4*)(t + pb);
        f4 sv = *(const f4*)(s + pb);
        f4 utv, usv;
        #pragma unroll
        for (int c = 0; c < 4; ++c) {
            utv[c] = (tv[c] - tmin) * tk;
            usv[c] = (sv[c] - smin) * sk;
        }
        __syncthreads();                 // previous compute done reading LDS
        *(f4*)&su_t[tid * 4] = utv;
        *(f4*)&su_s[tid * 4] = usv;
        __syncthreads();

        // --- compute phase: wave owns 256 points = 8 chunks of K=32 ---
        #pragma unroll
        for (int c = 0; c < 8; ++c) {
            const int kbase = wave * 256 + c * 32 + quad * 8;
            const f4* pt4 = (const f4*)&su_t[kbase];
            const f4* ps4 = (const f4*)&su_s[kbase];
            f4 ta = pt4[0], tb = pt4[1];
            f4 sa = ps4[0], sb = ps4[1];
            float ut[8] = {ta[0], ta[1], ta[2], ta[3], tb[0], tb[1], tb[2], tb[3]};
            float us[8] = {sa[0], sa[1], sa[2], sa[3], sb[0], sb[1], sb[2], sb[3]};

            half8 af[4], bf[4];
            #pragma unroll
            for (int mt = 0; mt < 4; ++mt) {
                float w[8];
                #pragma unroll
                for (int j = 0; j < 8; ++j) {
                    float d = ut[j] - mhat[mt];
                    w[j] = __builtin_amdgcn_exp2f(-(d * d));
                }
                af[mt] = pack8(w);
            }
            #pragma unroll
            for (int nt = 0; nt < 4; ++nt) {
                float w[8];
                #pragma unroll
                for (int j = 0; j < 8; ++j) {
                    float d = us[j] - mhat[nt];
                    w[j] = __builtin_amdgcn_exp2f(-(d * d));
                }
                bf[nt] = pack8(w);
            }
            #pragma unroll
            for (int mt = 0; mt < 4; ++mt)
                #pragma unroll
                for (int nt = 0; nt < 4; ++nt)
                    acc[mt][nt] = __builtin_amdgcn_mfma_f32_16x16x32_f16(
                        af[mt], bf[nt], acc[mt][nt], 0, 0, 0);
        }
    }
    __syncthreads();

    // --- combine 4 waves' 64x64 accumulators in LDS ---
    #pragma unroll
    for (int mt = 0; mt < 4; ++mt)
        #pragma unroll
        for (int nt = 0; nt < 4; ++nt)
            #pragma unroll
            for (int r = 0; r < 4; ++r) {
                int row = 16 * mt + 4 * quad + r;
                int col = 16 * nt + mlane;
                unsafeAtomicAdd(&lh[row * NBINS + col], acc[mt][nt][r]);
            }
    __syncthreads();

    if (staged) {
        f4* dst = (f4*)(bh + ((size_t)n * GX + bx) * HIST_ELEMS);
        const f4* l4 = (const f4*)lh;
        for (int i = tid; i < HIST_ELEMS / 4; i += 256) dst[i] = l4[i];
    } else {
        float* gh = hist + (size_t)n * HIST_ELEMS;
        for (int i = tid; i < HIST_ELEMS; i += 256) unsafeAtomicAdd(&gh[i], lh[i]);
    }
}

__global__ __launch_bounds__(256) void reduce_kernel(const float* __restrict__ bh,
                                                     float* __restrict__ hist) {
    const int g = blockIdx.x * 256 + threadIdx.x;   // 0..8191
    const int n = g >> 12, e = g & 4095;
    const float* p = bh + ((size_t)n * GX) * HIST_ELEMS + e;
    float sum = 0.0f;
    #pragma unroll 8
    for (int b = 0; b < GX; ++b) sum += p[(size_t)b * HIST_ELEMS];
    hist[g] = sum;
}

static __device__ __forceinline__ float block_reduce_sum(float v, float* buf) {
    for (int off = 32; off > 0; off >>= 1) v += __shfl_down(v, off, 64);
    const int lane = threadIdx.x & 63, wave = threadIdx.x >> 6;
    __syncthreads();
    if (lane == 0) buf[wave] = v;
    __syncthreads();
    return buf[0] + buf[1] + buf[2] + buf[3];
}

__global__ __launch_bounds__(256) void finalize_kernel(const float* __restrict__ ghist,
                                                       float* __restrict__ out) {
    __shared__ float buf[4];
    __shared__ float colp[4][NBINS];
    __shared__ float rowsum[NBINS], colsum[NBINS];
    const int tid = threadIdx.x;
    float acc = 0.0f;
    for (int n = 0; n < 2; ++n) {
        const float* h = ghist + n * HIST_ELEMS;
        {
            int r = tid >> 2, q = tid & 3;
            const float* hp = h + r * NBINS + q * 16;
            float sv = 0.0f;
            #pragma unroll
            for (int k = 0; k < 16; ++k) sv += hp[k];
            sv += __shfl_down(sv, 1, 64);
            sv += __shfl_down(sv, 2, 64);
            if (q == 0) rowsum[r] = sv;
        }
        {
            int c = tid & 63, g = tid >> 6;
            const float* hp = h + (g * 16) * NBINS + c;
            float sv = 0.0f;
            #pragma unroll
            for (int k = 0; k < 16; ++k) sv += hp[k * NBINS];
            colp[g][c] = sv;
        }
        __syncthreads();
        if (tid < NBINS)
            colsum[tid] = colp[0][tid] + colp[1][tid] + colp[2][tid] + colp[3][tid];
        __syncthreads();

        float tv = (tid < NBINS) ? rowsum[tid] : 0.0f;
        float total = block_reduce_sum(tv, buf);
        float inv = 1.0f / total;

        float ej = 0.0f;
        for (int i = tid; i < HIST_ELEMS; i += 256) {
            float p = h[i] * inv;
            ej += p * __logf(p + 1e-10f);
        }
        float entj = -block_reduce_sum(ej, buf);

        float em = 0.0f;
        if (tid < NBINS) {
            float p = rowsum[tid] * inv;
            em = p * __logf(p + 1e-10f);
        } else if (tid < 2 * NBINS) {
            float p = colsum[tid - NBINS] * inv;
            em = p * __logf(p + 1e-10f);
        }
        float ents = -block_reduce_sum(em, buf);

        acc += ents / entj;
        __syncthreads();
    }
    if (tid == 0) out[0] = -0.5f * acc;
}

extern "C" void kernel_launch(void* const* d_in, const int* in_sizes, int n_in,
                              void* d_out, int out_size, void* d_ws, size_t ws_size,
                              hipStream_t stream) {
    const float* tar = (const float*)d_in[0];
    const float* src = (const float*)d_in[1];
    const int N = 2;
    const int P = in_sizes[0] / N;  // 884736

    unsigned* mm = (unsigned*)d_ws;
    float* hist = (float*)((char*)d_ws + 256);
    float* bh = (float*)((char*)d_ws + 256 + 2 * HIST_ELEMS * sizeof(float));
    float* out = (float*)d_out;

    const size_t need = 256 + (size_t)2 * HIST_ELEMS * 4 + (size_t)2 * GX * HIST_ELEMS * 4;
    const int staged = (ws_size >= need) ? 1 : 0;

    init_ws_kernel<<<1, 256, 0, stream>>>(mm, hist);
    minmax_kernel<<<dim3(64, N, 2), 256, 0, stream>>>(tar, src, mm, P);
    mfma_hist_kernel<<<dim3(GX, N), 256, 0, stream>>>(tar, src, mm, bh, hist, P, staged);
    if (staged) reduce_kernel<<<32, 256, 0, stream>>>(bh, hist);
    finalize_kernel<<<1, 256, 0, stream>>>(hist, out);
}